// Round 4
// baseline (91.141 us; speedup 1.0000x reference)
//
#include <hip/hip_runtime.h>
#include <math.h>

#define NB 8
#define KC 64
#define S1C 5
#define CC 128
#define PP 1936
#define MM 320             /* KC*S1C */
#define PT 64
#define NPT 31             /* ceil(1936/64) */
#define NTILE (NB * NPT)   /* 248 */
#define ALPHAF 1500.0f
#define EPSF 1e-12f

/* ws layout (floats):
   [0, 65536)      cenPk: pre-split bf16 hi/lo cen B-fragments
                   [ks(4)][nt(32)][lane(64)][hi short8, lo short8] = 256 KB
   [65536, 66048)  gbias[512]  (m' = 8k+s padded; s>=5 -> -3e38)
   [66048, ...)    part[248][64][128] ; ps[248][64]                */
#define WS_CENPK 65536
#define WS_GBIAS 512
#define WS_HDR   (WS_CENPK + WS_GBIAS)
#define WS_PART  ((size_t)NTILE * KC * CC)
#define WS_MAIN_FLOATS (WS_HDR + WS_PART + (size_t)NTILE * KC)

typedef __attribute__((ext_vector_type(8))) short short8;
typedef __attribute__((ext_vector_type(4))) float f32x4;

/* pack fp32 -> (bf16_hi << 16) | bf16_lo  (hi = truncate, lo = residual) */
__device__ __forceinline__ unsigned pack_bf16s(float x) {
    unsigned u  = __float_as_uint(x);
    unsigned hi = u & 0xffff0000u;
    float lo    = x - __uint_as_float(hi);
    return hi | (__float_as_uint(lo) >> 16);
}

__device__ __forceinline__ void unpack8(const int4 q0, const int4 q1,
                                        short8& h, short8& l) {
    const int d[8] = {q0.x, q0.y, q0.z, q0.w, q1.x, q1.y, q1.z, q1.w};
#pragma unroll
    for (int j = 0; j < 8; ++j) {
        h[j] = (short)((unsigned)d[j] >> 16);
        l[j] = (short)((unsigned)d[j] & 0xffffu);
    }
}

__device__ __forceinline__ void split8(const float4 a, const float4 b,
                                       short8& h, short8& l) {
    const float f[8] = {a.x, a.y, a.z, a.w, b.x, b.y, b.z, b.w};
#pragma unroll
    for (int j = 0; j < 8; ++j) {
        const unsigned u  = __float_as_uint(f[j]);
        const unsigned hi = u & 0xffff0000u;
        const float lo    = f[j] - __uint_as_float(hi);
        h[j] = (short)(hi >> 16);
        l[j] = (short)(__float_as_uint(lo) >> 16);
    }
}

// ---------------------------------------------------------------------------
// k0: precompute bias[512] and pre-split bf16 hi/lo cen fragments in MFMA
// B-operand lane layout. 32 blocks (one per m'-tile nt) x 64 threads.
// ---------------------------------------------------------------------------
__global__ __launch_bounds__(64) void k0_pack(
    const float* __restrict__ cen, unsigned* __restrict__ cenPk,
    float* __restrict__ gbias)
{
    const int nt   = blockIdx.x;      // 0..31
    const int l    = threadIdx.x;     // 0..63
    const int l15  = l & 15;
    const int quad = l >> 4;
    const int mp   = nt * 16 + l15;   // padded m' = 8k+s
    const int s    = mp & 7;
    const bool valid = (s < 5);
    const int wrow = 5 * (mp >> 3) + s;
    short8* dst8 = (short8*)cenPk;
    float ss = 0.f;
#pragma unroll
    for (int ks = 0; ks < 4; ++ks) {
        float4 v0 = make_float4(0.f, 0.f, 0.f, 0.f), v1 = v0;
        if (valid) {
            const float* wp = cen + (size_t)wrow * CC + ks * 32 + quad * 8;
            v0 = *(const float4*)wp;
            v1 = *(const float4*)(wp + 4);
        }
        ss += v0.x * v0.x + v0.y * v0.y + v0.z * v0.z + v0.w * v0.w
            + v1.x * v1.x + v1.y * v1.y + v1.z * v1.z + v1.w * v1.w;
        short8 h, lo;
        split8(v0, v1, h, lo);
        const int base = ((ks * 32 + nt) * 64 + l) * 2;
        dst8[base]     = h;
        dst8[base + 1] = lo;
    }
    ss += __shfl_xor(ss, 16);
    ss += __shfl_xor(ss, 32);
    if (quad == 0) gbias[mp] = valid ? (-ALPHAF * sqrtf(ss)) : -3.0e38f;
}

// ---------------------------------------------------------------------------
// k1: per (n, p-tile of 64), 1024 threads = 16 waves, 3 barriers.
//  - x loaded from global ONCE: phase-0 mapping (c = tid>>3, 8 consecutive p)
//    produces exactly the packed words phase-3's [c][68] layout needs; they
//    are held in 8 VGPRs and ds_written right after B2 (no second HBM read,
//    no second pack pass).
//  - ks=0 cenPk B-frags + bias prefetched at kernel start (independent of
//    LDS staging -> latency hidden under phase 0 + B1).
//  - sa written as a coalesced tail from war (sa = wa - 1, bf16 hi+lo
//    reconstruction, err ~1.5e-5); scattered is_s0 writes removed from the
//    softmax inner loop.
// ---------------------------------------------------------------------------
__global__ __launch_bounds__(1024, 4) void k1_main(
    const float* __restrict__ x, const unsigned* __restrict__ cenPk,
    const float* __restrict__ gbias,
    float* __restrict__ sa_out, float* __restrict__ outC,
    float* __restrict__ outS, int mode)
{
    __shared__ unsigned xbuf[CC * 68];   // 34816 B; phase1: [p][132] packed x^T; phase3: [c][68] packed x
    __shared__ unsigned war[KC * 68];    // 17408 B packed wa [k][p]
    __shared__ float2   ap[16 * 66];     //  8448 B alpha partials [wid][p]

    const int tid  = threadIdx.x;
    const int lane = tid & 63;
    const int wid  = tid >> 6;           // 0..15
    const int quad = lane >> 4;
    const int l15  = lane & 15;
    const int bx   = blockIdx.x;
    const int n    = bx / NPT;
    const int pt   = bx - n * NPT;
    const int p0   = pt * PT;

    // ---- early prefetches (no LDS dependency): bias + ks=0 B-frags ----
    const float bv0 = gbias[(2 * wid + 0) * 16 + l15];
    const float bv1 = gbias[(2 * wid + 1) * 16 + l15];
    const short8* cpk8 = (const short8*)cenPk;
    short8 bh0[2], bl0[2];
#pragma unroll
    for (int i = 0; i < 2; ++i) {
        const int boff = ((2 * wid + i) * 64 + lane) * 2;
        bh0[i] = cpk8[boff];
        bl0[i] = cpk8[boff + 1];
    }

    // ---- phase 0: stage x -> xbuf[p][132]; keep packed words in regs ----
    const float* xn = x + (size_t)n * CC * PP;
    const int sc  = tid >> 3;            // 0..127 (channel)
    const int spo = (tid & 7) * 8;       // 0..56  (p offset, 8 consecutive)
    unsigned pk[8];
    {
        float4 v0 = make_float4(0.f, 0.f, 0.f, 0.f), v1 = v0;
        if (p0 + spo < PP) {             // PP % 8 == 0: chunk full or empty
            const float* src = xn + (size_t)sc * PP + p0 + spo;
            v0 = *(const float4*)src;
            v1 = *(const float4*)(src + 4);
        }
        pk[0] = pack_bf16s(v0.x); pk[1] = pack_bf16s(v0.y);
        pk[2] = pack_bf16s(v0.z); pk[3] = pack_bf16s(v0.w);
        pk[4] = pack_bf16s(v1.x); pk[5] = pack_bf16s(v1.y);
        pk[6] = pack_bf16s(v1.z); pk[7] = pack_bf16s(v1.w);
#pragma unroll
        for (int j = 0; j < 8; ++j) xbuf[(spo + j) * 132 + sc] = pk[j];
    }
    __syncthreads();

    // ---- phase 1: logits MFMA ----
    f32x4 dacc[4][2];
#pragma unroll
    for (int a = 0; a < 4; ++a) {
        dacc[a][0] = (f32x4){0.f, 0.f, 0.f, 0.f};
        dacc[a][1] = (f32x4){0.f, 0.f, 0.f, 0.f};
    }

    auto mfma_step = [&](const int ksoff, const short8 bh[2], const short8 bl[2]) {
#pragma unroll
        for (int a = 0; a < 4; ++a) {
            const int abase = (a * 16 + l15) * 132 + ksoff + quad * 8;
            const int4 q0 = *(const int4*)(&xbuf[abase]);
            const int4 q1 = *(const int4*)(&xbuf[abase + 4]);
            short8 ah, al;
            unpack8(q0, q1, ah, al);
#pragma unroll
            for (int i = 0; i < 2; ++i) {
                dacc[a][i] = __builtin_amdgcn_mfma_f32_16x16x32_bf16(ah, bh[i], dacc[a][i], 0, 0, 0);
                dacc[a][i] = __builtin_amdgcn_mfma_f32_16x16x32_bf16(ah, bl[i], dacc[a][i], 0, 0, 0);
                dacc[a][i] = __builtin_amdgcn_mfma_f32_16x16x32_bf16(al, bh[i], dacc[a][i], 0, 0, 0);
            }
        }
    };

    mfma_step(0, bh0, bl0);
#pragma unroll 1
    for (int ks = 1; ks < 4; ++ks) {
        short8 bh[2], bl[2];
#pragma unroll
        for (int i = 0; i < 2; ++i) {
            const int boff = ((ks * 32 + 2 * wid + i) * 64 + lane) * 2;
            bh[i] = cpk8[boff];
            bl[i] = cpk8[boff + 1];
        }
        mfma_step(ks * 32, bh, bl);
    }

    // lg in place: lg = 2*ALPHA*dot + bias (invalid cols -> -3e38)
#pragma unroll
    for (int a = 0; a < 4; ++a)
#pragma unroll
        for (int r = 0; r < 4; ++r) {
            dacc[a][0][r] = 2.f * ALPHAF * dacc[a][0][r] + bv0;
            dacc[a][1][r] = 2.f * ALPHAF * dacc[a][1][r] + bv1;
        }

    // alpha partials over this wave's 4 k (i-regs x shfl_xor 8), s0 lanes hold lg0
#pragma unroll
    for (int a = 0; a < 4; ++a) {
        f32x4 mx4, se4;
#pragma unroll
        for (int r = 0; r < 4; ++r) {
            float m_ = fmaxf(dacc[a][0][r], dacc[a][1][r]);
            m_ = fmaxf(m_, __shfl_xor(m_, 8));
            float se = __expf(dacc[a][0][r] - m_) + __expf(dacc[a][1][r] - m_);
            se += __shfl_xor(se, 8);
            mx4[r] = m_; se4[r] = se;
        }
        if (l15 == 0) {
#pragma unroll
            for (int r = 0; r < 4; ++r)
                ap[wid * 66 + a * 16 + 4 * quad + r] = make_float2(mx4[r], se4[r]);
        }
    }
    __syncthreads();

    // ---- phase 2 ----
    // xc layout write from carried regs (all phase-1 xbuf reads are done)
    *(int4*)(&xbuf[sc * 68 + spo])     = *(const int4*)&pk[0];
    *(int4*)(&xbuf[sc * 68 + spo + 4]) = *(const int4*)&pk[4];

    // alpha finalize (lane = p)
    float gmv, arv;
    {
        float gm = -3.0e38f;
#pragma unroll
        for (int w = 0; w < 16; ++w) gm = fmaxf(gm, ap[w * 66 + lane].x);
        float s = 0.f;
#pragma unroll
        for (int w = 0; w < 16; ++w) {
            const float2 v = ap[w * 66 + lane];
            s += v.y * __expf(v.x - gm);
        }
        gmv = gm; arv = 1.0f / s;
    }

    // beta + sa + wa pack -> war; psum
    float psum[2] = {0.f, 0.f};
    const bool is_s0 = ((l15 & 7) == 0);
#pragma unroll
    for (int a = 0; a < 4; ++a) {
#pragma unroll
        for (int i = 0; i < 2; ++i) {
            const f32x4 lg = dacc[a][i];
            unsigned wpk[4];
#pragma unroll
            for (int r = 0; r < 4; ++r) {
                float m_ = lg[r];
                m_ = fmaxf(m_, __shfl_xor(m_, 1));
                m_ = fmaxf(m_, __shfl_xor(m_, 2));
                m_ = fmaxf(m_, __shfl_xor(m_, 4));
                const float e_ = __expf(lg[r] - m_);
                float d_ = e_;
                d_ += __shfl_xor(d_, 1);
                d_ += __shfl_xor(d_, 2);
                d_ += __shfl_xor(d_, 4);
                const int p = a * 16 + 4 * quad + r;
                const float gm_p = __shfl(gmv, p);
                const float ar_p = __shfl(arv, p);
                const float sa = __expf(lg[r] - gm_p) * ar_p * (e_ / d_);
                const bool pvalid = (p0 + p) < PP;
                const float wa = pvalid ? (1.0f + sa) : 0.0f;
                wpk[r] = pack_bf16s(wa);
                psum[i] += wa;
            }
            const int k = 4 * wid + 2 * i + (l15 >> 3);
            if (is_s0)
                *(int4*)(&war[k * 68 + a * 16 + 4 * quad]) = *(const int4*)wpk;
        }
    }
#pragma unroll
    for (int i = 0; i < 2; ++i) {
        float s = psum[i];
        s += __shfl_xor(s, 16);
        s += __shfl_xor(s, 32);
        if (is_s0 && quad == 0) {
            const int k = 4 * wid + 2 * i + (l15 >> 3);
            if (mode == 0) outS[(size_t)bx * KC + k] = s;
            else           atomicAdd(&outS[(size_t)n * KC + k], s);
        }
    }
    __syncthreads();

    // ---- phase 3: stage-C MFMA: C[k][c] = sum_p wa*x ----
    const int kt  = wid & 3;
    const int ct0 = (wid >> 2) * 2;
    f32x4 cacc[2];
    cacc[0] = (f32x4){0.f, 0.f, 0.f, 0.f};
    cacc[1] = (f32x4){0.f, 0.f, 0.f, 0.f};
#pragma unroll
    for (int ks = 0; ks < 64; ks += 32) {
        const int abase = (kt * 16 + l15) * 68 + ks + quad * 8;
        const int4 qa0 = *(const int4*)(&war[abase]);
        const int4 qa1 = *(const int4*)(&war[abase + 4]);
        short8 ah, al;
        unpack8(qa0, qa1, ah, al);
#pragma unroll
        for (int t = 0; t < 2; ++t) {
            const int c = (ct0 + t) * 16 + l15;
            const int bbase = c * 68 + ks + quad * 8;
            const int4 qb0 = *(const int4*)(&xbuf[bbase]);
            const int4 qb1 = *(const int4*)(&xbuf[bbase + 4]);
            short8 bh, bl;
            unpack8(qb0, qb1, bh, bl);
            cacc[t] = __builtin_amdgcn_mfma_f32_16x16x32_bf16(ah, bh, cacc[t], 0, 0, 0);
            cacc[t] = __builtin_amdgcn_mfma_f32_16x16x32_bf16(ah, bl, cacc[t], 0, 0, 0);
            cacc[t] = __builtin_amdgcn_mfma_f32_16x16x32_bf16(al, bh, cacc[t], 0, 0, 0);
        }
    }
    if (mode == 0) {
        float* dst = outC + (size_t)bx * KC * CC;
#pragma unroll
        for (int t = 0; t < 2; ++t) {
            const int c = (ct0 + t) * 16 + l15;
#pragma unroll
            for (int r = 0; r < 4; ++r)
                dst[(kt * 16 + 4 * quad + r) * CC + c] = cacc[t][r];
        }
    } else {
        float* dst = outC + (size_t)n * KC * CC;
#pragma unroll
        for (int t = 0; t < 2; ++t) {
            const int c = (ct0 + t) * 16 + l15;
#pragma unroll
            for (int r = 0; r < 4; ++r)
                atomicAdd(&dst[(kt * 16 + 4 * quad + r) * CC + c], cacc[t][r]);
        }
    }

    // ---- sa tail: coalesced write, sa = (hi+lo of war) - 1 ----
    {
        float* san = sa_out + (size_t)n * KC * PP;
        const int k  = tid >> 4;          // 0..63
        const int p4 = (tid & 15) * 4;    // 0..60
        const int pg = p0 + p4;
        if (pg < PP) {
            const int4 q = *(const int4*)(&war[k * 68 + p4]);
            const int d[4] = {q.x, q.y, q.z, q.w};
            float4 sv;
            float* svp = &sv.x;
#pragma unroll
            for (int j = 0; j < 4; ++j) {
                const unsigned u = (unsigned)d[j];
                const float wa = __uint_as_float(u & 0xffff0000u)
                               + __uint_as_float(u << 16);
                svp[j] = wa - 1.0f;
            }
            *(float4*)(&san[(size_t)k * PP + pg]) = sv;
        }
    }
}

// ---------------------------------------------------------------------------
// k2 (slab mode): reduce 31 partial slabs, subtract rep*Swa, normalize, /8
// ---------------------------------------------------------------------------
__global__ __launch_bounds__(128) void k2_slab(
    const float* __restrict__ part, const float* __restrict__ ps,
    const float* __restrict__ cen, float* __restrict__ flat)
{
    __shared__ float w2[2];
    const int b = blockIdx.x;        // n*64 + k
    const int n = b >> 6;
    const int k = b & 63;
    const int c = threadIdx.x;       // 0..127
    const float* pb = part + (size_t)n * NPT * KC * CC + (size_t)k * CC + c;
    float v = 0.f;
#pragma unroll 8
    for (int pt = 0; pt < NPT; ++pt) v += pb[(size_t)pt * KC * CC];
    const float* psb = ps + (size_t)n * NPT * KC + k;
    float sw = 0.f;
#pragma unroll
    for (int pt = 0; pt < NPT; ++pt) sw += psb[(size_t)pt * KC];
    v -= cen[(size_t)k * S1C * CC + c] * sw;

    float ss = v * v;
#pragma unroll
    for (int off = 32; off > 0; off >>= 1) ss += __shfl_down(ss, off);
    if ((c & 63) == 0) w2[c >> 6] = ss;
    __syncthreads();
    const float norm = sqrtf(w2[0] + w2[1]);
    // flat-level norm is exactly sqrt(64)=8 (every row unit-norm, >> EPS)
    const float scale = 1.0f / (fmaxf(norm, EPSF) * 8.0f);
    flat[(size_t)b * CC + c] = v * scale;
}

// ---------------------------------------------------------------------------
// k2 (fallback/atomic mode)
// ---------------------------------------------------------------------------
__global__ __launch_bounds__(128) void k2_final(
    const float* __restrict__ accC, const float* __restrict__ accS,
    const float* __restrict__ cen, float* __restrict__ flat)
{
    __shared__ float w2[2];
    const int b = blockIdx.x;
    const int k = b & 63;
    const int c = threadIdx.x;
    const float v = accC[(size_t)b * CC + c] -
                    cen[(size_t)k * S1C * CC + c] * accS[b];
    float ss = v * v;
#pragma unroll
    for (int off = 32; off > 0; off >>= 1) ss += __shfl_down(ss, off);
    if ((c & 63) == 0) w2[c >> 6] = ss;
    __syncthreads();
    const float norm = sqrtf(w2[0] + w2[1]);
    const float scale = 1.0f / (fmaxf(norm, EPSF) * 8.0f);
    flat[(size_t)b * CC + c] = v * scale;
}

// ---------------------------------------------------------------------------
extern "C" void kernel_launch(void* const* d_in, const int* in_sizes, int n_in,
                              void* d_out, int out_size, void* d_ws, size_t ws_size,
                              hipStream_t stream) {
    const float* x   = (const float*)d_in[0];   // [8][128][44][44]
    const float* cen = (const float*)d_in[1];   // [64][5][128]
    float* out  = (float*)d_out;
    float* flat = out;                           // [8][8192]
    float* sa   = out + (size_t)NB * KC * CC;    // [8][64][1][1936]
    float* ws   = (float*)d_ws;

    unsigned* cenPk = (unsigned*)ws;
    float*    gbias = ws + WS_CENPK;

    if (ws_size >= WS_MAIN_FLOATS * 4) {
        float* part = ws + WS_HDR;
        float* ps   = part + WS_PART;
        k0_pack<<<32, 64, 0, stream>>>(cen, cenPk, gbias);
        k1_main<<<NTILE, 1024, 0, stream>>>(x, cenPk, gbias, sa, part, ps, 0);
        k2_slab<<<NB * KC, 128, 0, stream>>>(part, ps, cen, flat);
    } else {
        float* accC = ws + WS_HDR;
        float* accS = accC + (size_t)NB * KC * CC;
        hipMemsetAsync(accC, 0, (size_t)(NB * KC * CC + NB * KC) * 4, stream);
        k0_pack<<<32, 64, 0, stream>>>(cen, cenPk, gbias);
        k1_main<<<NTILE, 1024, 0, stream>>>(x, cenPk, gbias, sa, accC, accS, 1);
        k2_final<<<NB * KC, 128, 0, stream>>>(accC, accS, cen, flat);
    }
}

// Round 5
// 80.620 us; speedup vs baseline: 1.1305x; 1.1305x over previous
//
#include <hip/hip_runtime.h>
#include <math.h>

#define NB 8
#define KC 64
#define S1C 5
#define CC 128
#define PP 1936
#define MM 320             /* KC*S1C */
#define PT 64
#define NPT 31             /* ceil(1936/64) */
#define NTILE (NB * NPT)   /* 248 */
#define ALPHAF 1500.0f
#define EPSF 1e-12f

/* ws layout (floats):
   [0, 65536)      cenPk: pre-split bf16 hi/lo cen fragments
                   [ks(4)][nt(32)][lane(64)][hi short8, lo short8] = 256 KB
   [65536, 66048)  gbias[512]  (m' = 8k+s padded; s>=5 -> -3e38)
   [66048, ...)    part[248][64][128] ; ps[248][64]                */
#define WS_CENPK 65536
#define WS_GBIAS 512
#define WS_HDR   (WS_CENPK + WS_GBIAS)
#define WS_PART  ((size_t)NTILE * KC * CC)
#define WS_MAIN_FLOATS (WS_HDR + WS_PART + (size_t)NTILE * KC)

typedef __attribute__((ext_vector_type(8))) short short8;
typedef __attribute__((ext_vector_type(4))) float f32x4;

/* pack fp32 -> (bf16_hi << 16) | bf16_lo  (hi = truncate, lo = residual) */
__device__ __forceinline__ unsigned pack_bf16s(float x) {
    unsigned u  = __float_as_uint(x);
    unsigned hi = u & 0xffff0000u;
    float lo    = x - __uint_as_float(hi);
    return hi | (__float_as_uint(lo) >> 16);
}

__device__ __forceinline__ void unpack8(const int4 q0, const int4 q1,
                                        short8& h, short8& l) {
    const int d[8] = {q0.x, q0.y, q0.z, q0.w, q1.x, q1.y, q1.z, q1.w};
#pragma unroll
    for (int j = 0; j < 8; ++j) {
        h[j] = (short)((unsigned)d[j] >> 16);
        l[j] = (short)((unsigned)d[j] & 0xffffu);
    }
}

__device__ __forceinline__ void split8(const float4 a, const float4 b,
                                       short8& h, short8& l) {
    const float f[8] = {a.x, a.y, a.z, a.w, b.x, b.y, b.z, b.w};
#pragma unroll
    for (int j = 0; j < 8; ++j) {
        const unsigned u  = __float_as_uint(f[j]);
        const unsigned hi = u & 0xffff0000u;
        const float lo    = f[j] - __uint_as_float(hi);
        h[j] = (short)(hi >> 16);
        l[j] = (short)(__float_as_uint(lo) >> 16);
    }
}

// ---------------------------------------------------------------------------
// k0: precompute bias[512] and pre-split bf16 hi/lo cen fragments in MFMA
// lane layout. 32 blocks (one per m'-tile nt) x 64 threads.
// ---------------------------------------------------------------------------
__global__ __launch_bounds__(64) void k0_pack(
    const float* __restrict__ cen, unsigned* __restrict__ cenPk,
    float* __restrict__ gbias)
{
    const int nt   = blockIdx.x;      // 0..31
    const int l    = threadIdx.x;     // 0..63
    const int l15  = l & 15;
    const int quad = l >> 4;
    const int mp   = nt * 16 + l15;   // padded m' = 8k+s
    const int s    = mp & 7;
    const bool valid = (s < 5);
    const int wrow = 5 * (mp >> 3) + s;
    short8* dst8 = (short8*)cenPk;
    float ss = 0.f;
#pragma unroll
    for (int ks = 0; ks < 4; ++ks) {
        float4 v0 = make_float4(0.f, 0.f, 0.f, 0.f), v1 = v0;
        if (valid) {
            const float* wp = cen + (size_t)wrow * CC + ks * 32 + quad * 8;
            v0 = *(const float4*)wp;
            v1 = *(const float4*)(wp + 4);
        }
        ss += v0.x * v0.x + v0.y * v0.y + v0.z * v0.z + v0.w * v0.w
            + v1.x * v1.x + v1.y * v1.y + v1.z * v1.z + v1.w * v1.w;
        short8 h, lo;
        split8(v0, v1, h, lo);
        const int base = ((ks * 32 + nt) * 64 + l) * 2;
        dst8[base]     = h;
        dst8[base + 1] = lo;
    }
    ss += __shfl_xor(ss, 16);
    ss += __shfl_xor(ss, 32);
    if (quad == 0) gbias[mp] = valid ? (-ALPHAF * sqrtf(ss)) : -3.0e38f;
}

// ---------------------------------------------------------------------------
// k1: per (n, p-tile of 64), 1024 threads = 16 waves, 3 barriers.
// R5: SWAPPED MFMA operands -> D[m'][p] = cen . x^T. The s-dimension now
// lives in accumulator registers (even quads: s=0..3 in r; odd quads donate
// s=4 via one shfl_xor(16)), so the beta softmax is in-register math with
// ONE shfl per (a,i) instead of 32 DS ops. Alpha partials: 2 shfl per a.
// Cuts phase-2 DS-pipe traffic ~4x on the (per-CU serial) critical path.
// ---------------------------------------------------------------------------
__global__ __launch_bounds__(1024, 4) void k1_main(
    const float* __restrict__ x, const unsigned* __restrict__ cenPk,
    const float* __restrict__ gbias,
    float* __restrict__ sa_out, float* __restrict__ outC,
    float* __restrict__ outS, int mode)
{
    __shared__ unsigned xbuf[CC * 68];   // 34816 B; phase1: [p][132] packed x^T; phase3: [c][68] packed x
    __shared__ unsigned war[KC * 68];    // 17408 B packed wa [k][p]
    __shared__ float2   ap[16 * 66];     //  8448 B alpha partials [wid][p]

    const int tid  = threadIdx.x;
    const int lane = tid & 63;
    const int wid  = tid >> 6;           // 0..15
    const int quad = lane >> 4;
    const int l15  = lane & 15;
    const int bx   = blockIdx.x;
    const int n    = bx / NPT;
    const int pt   = bx - n * NPT;
    const int p0   = pt * PT;

    // ---- early prefetches (no LDS dependency): bias rows + ks=0 cen frags ----
    float4 bvf[2];
#pragma unroll
    for (int i = 0; i < 2; ++i)
        bvf[i] = *(const float4*)(gbias + (2 * wid + i) * 16 + quad * 4);
    const short8* cpk8 = (const short8*)cenPk;
    short8 ch0[2], cl0[2];
#pragma unroll
    for (int i = 0; i < 2; ++i) {
        const int boff = ((2 * wid + i) * 64 + lane) * 2;
        ch0[i] = cpk8[boff];
        cl0[i] = cpk8[boff + 1];
    }

    // ---- phase 0: stage x -> xbuf[p][132]; keep packed words in regs ----
    const float* xn = x + (size_t)n * CC * PP;
    const int sc  = tid >> 3;            // 0..127 (channel)
    const int spo = (tid & 7) * 8;       // 0..56  (p offset, 8 consecutive)
    unsigned pk[8];
    {
        float4 v0 = make_float4(0.f, 0.f, 0.f, 0.f), v1 = v0;
        if (p0 + spo < PP) {             // PP % 8 == 0: chunk full or empty
            const float* src = xn + (size_t)sc * PP + p0 + spo;
            v0 = *(const float4*)src;
            v1 = *(const float4*)(src + 4);
        }
        pk[0] = pack_bf16s(v0.x); pk[1] = pack_bf16s(v0.y);
        pk[2] = pack_bf16s(v0.z); pk[3] = pack_bf16s(v0.w);
        pk[4] = pack_bf16s(v1.x); pk[5] = pack_bf16s(v1.y);
        pk[6] = pack_bf16s(v1.z); pk[7] = pack_bf16s(v1.w);
#pragma unroll
        for (int j = 0; j < 8; ++j) xbuf[(spo + j) * 132 + sc] = pk[j];
    }
    __syncthreads();

    // ---- phase 1: logits MFMA (swapped: A = cen, B = x) ----
    // D[m'][p]: lane holds col p = a*16 + l15; rows m'off = quad*4 + r.
    f32x4 dacc[4][2];
#pragma unroll
    for (int a = 0; a < 4; ++a) {
        dacc[a][0] = (f32x4){0.f, 0.f, 0.f, 0.f};
        dacc[a][1] = (f32x4){0.f, 0.f, 0.f, 0.f};
    }

    auto mfma_step = [&](const int ksoff, const short8 ch[2], const short8 cl[2]) {
#pragma unroll
        for (int a = 0; a < 4; ++a) {
            const int abase = (a * 16 + l15) * 132 + ksoff + quad * 8;
            const int4 q0 = *(const int4*)(&xbuf[abase]);
            const int4 q1 = *(const int4*)(&xbuf[abase + 4]);
            short8 xh, xl;
            unpack8(q0, q1, xh, xl);
#pragma unroll
            for (int i = 0; i < 2; ++i) {
                dacc[a][i] = __builtin_amdgcn_mfma_f32_16x16x32_bf16(ch[i], xh, dacc[a][i], 0, 0, 0);
                dacc[a][i] = __builtin_amdgcn_mfma_f32_16x16x32_bf16(ch[i], xl, dacc[a][i], 0, 0, 0);
                dacc[a][i] = __builtin_amdgcn_mfma_f32_16x16x32_bf16(cl[i], xh, dacc[a][i], 0, 0, 0);
            }
        }
    };

    mfma_step(0, ch0, cl0);
#pragma unroll 1
    for (int ks = 1; ks < 4; ++ks) {
        short8 ch[2], cl[2];
#pragma unroll
        for (int i = 0; i < 2; ++i) {
            const int boff = ((ks * 32 + 2 * wid + i) * 64 + lane) * 2;
            ch[i] = cpk8[boff];
            cl[i] = cpk8[boff + 1];
        }
        mfma_step(ks * 32, ch, cl);
    }

    // lg in place: lg = 2*ALPHA*dot + bias[m'], m' = (2wid+i)*16 + quad*4 + r
#pragma unroll
    for (int i = 0; i < 2; ++i) {
        const float* bvp = (const float*)&bvf[i];
#pragma unroll
        for (int a = 0; a < 4; ++a)
#pragma unroll
            for (int r = 0; r < 4; ++r)
                dacc[a][i][r] = 2.f * ALPHAF * dacc[a][i][r] + bvp[r];
    }

    // alpha partials: per a, wave's 4 k's; lg0 (s=0) lives at reg0 of even
    // quads (quad0: k=4wid+2i, quad2: k=4wid+2i+1); combine across quad pair
    // via shfl_xor 32. quad0 lanes store [wid][p].
#pragma unroll
    for (int a = 0; a < 4; ++a) {
        const float l0 = dacc[a][0][0];
        const float l1 = dacc[a][1][0];
        const float m2 = fmaxf(l0, l1);
        const float mo = __shfl_xor(m2, 32);
        const float m4 = fmaxf(m2, mo);
        float se = __expf(l0 - m4) + __expf(l1 - m4);
        se += __shfl_xor(se, 32);
        if ((lane & 48) == 0) ap[wid * 66 + a * 16 + l15] = make_float2(m4, se);
    }
    __syncthreads();

    // ---- phase 2 ----
    // xc layout write from carried regs (all phase-1 xbuf reads are done)
    *(int4*)(&xbuf[sc * 68 + spo])     = *(const int4*)&pk[0];
    *(int4*)(&xbuf[sc * 68 + spo + 4]) = *(const int4*)&pk[4];

    // alpha finalize (lane = p)
    float gmv, arv;
    {
        float gm = -3.0e38f;
#pragma unroll
        for (int w = 0; w < 16; ++w) gm = fmaxf(gm, ap[w * 66 + lane].x);
        float s = 0.f;
#pragma unroll
        for (int w = 0; w < 16; ++w) {
            const float2 v = ap[w * 66 + lane];
            s += v.y * __expf(v.x - gm);
        }
        gmv = gm; arv = 1.0f / s;
    }

    // beta + sa + wa: in-register 5-term softmax; one shfl per (a,i).
    const int  kb  = 4 * wid + ((lane >> 5) & 1);   // even-quad k = kb + 2i
    const bool evq = ((lane & 16) == 0);
    float psum2[2] = {0.f, 0.f};
#pragma unroll
    for (int a = 0; a < 4; ++a) {
        const int p = a * 16 + l15;
        const float gm_p = __shfl(gmv, p);
        const float ar_p = __shfl(arv, p);
        const bool pvalid = (p0 + p) < PP;
#pragma unroll
        for (int i = 0; i < 2; ++i) {
            const f32x4 lg = dacc[a][i];
            const float s4 = __shfl_xor(lg[0], 16);  // partner quad's s=4 logit
            float m5 = fmaxf(fmaxf(lg[0], lg[1]), fmaxf(lg[2], lg[3]));
            m5 = fmaxf(m5, s4);
            const float e0 = __expf(lg[0] - m5);
            const float d5 = e0 + __expf(lg[1] - m5) + __expf(lg[2] - m5)
                           + __expf(lg[3] - m5) + __expf(s4 - m5);
            const float sa = __expf(lg[0] - gm_p) * ar_p * (e0 / d5);
            const float wa = pvalid ? (1.0f + sa) : 0.0f;
            if (evq) war[(kb + 2 * i) * 68 + p] = pack_bf16s(wa);
            psum2[i] += wa;
        }
    }
#pragma unroll
    for (int i = 0; i < 2; ++i) {
        float s = psum2[i];
        s += __shfl_xor(s, 1);
        s += __shfl_xor(s, 2);
        s += __shfl_xor(s, 4);
        s += __shfl_xor(s, 8);
        if ((lane & 31) == 0) {                      // l15==0 on even quads
            const int k = kb + 2 * i;
            if (mode == 0) outS[(size_t)bx * KC + k] = s;
            else           atomicAdd(&outS[(size_t)n * KC + k], s);
        }
    }
    __syncthreads();

    // ---- phase 3: stage-C MFMA: C[k][c] = sum_p wa*x ----
    const int kt  = wid & 3;
    const int ct0 = (wid >> 2) * 2;
    f32x4 cacc[2];
    cacc[0] = (f32x4){0.f, 0.f, 0.f, 0.f};
    cacc[1] = (f32x4){0.f, 0.f, 0.f, 0.f};
#pragma unroll
    for (int ks = 0; ks < 64; ks += 32) {
        const int abase = (kt * 16 + l15) * 68 + ks + quad * 8;
        const int4 qa0 = *(const int4*)(&war[abase]);
        const int4 qa1 = *(const int4*)(&war[abase + 4]);
        short8 ah, al;
        unpack8(qa0, qa1, ah, al);
#pragma unroll
        for (int t = 0; t < 2; ++t) {
            const int c = (ct0 + t) * 16 + l15;
            const int bbase = c * 68 + ks + quad * 8;
            const int4 qb0 = *(const int4*)(&xbuf[bbase]);
            const int4 qb1 = *(const int4*)(&xbuf[bbase + 4]);
            short8 bh, bl;
            unpack8(qb0, qb1, bh, bl);
            cacc[t] = __builtin_amdgcn_mfma_f32_16x16x32_bf16(ah, bh, cacc[t], 0, 0, 0);
            cacc[t] = __builtin_amdgcn_mfma_f32_16x16x32_bf16(ah, bl, cacc[t], 0, 0, 0);
            cacc[t] = __builtin_amdgcn_mfma_f32_16x16x32_bf16(al, bh, cacc[t], 0, 0, 0);
        }
    }
    if (mode == 0) {
        float* dst = outC + (size_t)bx * KC * CC;
#pragma unroll
        for (int t = 0; t < 2; ++t) {
            const int c = (ct0 + t) * 16 + l15;
#pragma unroll
            for (int r = 0; r < 4; ++r)
                dst[(kt * 16 + 4 * quad + r) * CC + c] = cacc[t][r];
        }
    } else {
        float* dst = outC + (size_t)n * KC * CC;
#pragma unroll
        for (int t = 0; t < 2; ++t) {
            const int c = (ct0 + t) * 16 + l15;
#pragma unroll
            for (int r = 0; r < 4; ++r)
                atomicAdd(&dst[(kt * 16 + 4 * quad + r) * CC + c], cacc[t][r]);
        }
    }

    // ---- sa tail: coalesced write, sa = (hi+lo of war) - 1 ----
    {
        float* san = sa_out + (size_t)n * KC * PP;
        const int k  = tid >> 4;          // 0..63
        const int p4 = (tid & 15) * 4;    // 0..60
        const int pg = p0 + p4;
        if (pg < PP) {
            const int4 q = *(const int4*)(&war[k * 68 + p4]);
            const int d[4] = {q.x, q.y, q.z, q.w};
            float4 sv;
            float* svp = &sv.x;
#pragma unroll
            for (int j = 0; j < 4; ++j) {
                const unsigned u = (unsigned)d[j];
                const float wa = __uint_as_float(u & 0xffff0000u)
                               + __uint_as_float(u << 16);
                svp[j] = wa - 1.0f;
            }
            *(float4*)(&san[(size_t)k * PP + pg]) = sv;
        }
    }
}

// ---------------------------------------------------------------------------
// k2 (slab mode): reduce 31 partial slabs, subtract rep*Swa, normalize, /8
// ---------------------------------------------------------------------------
__global__ __launch_bounds__(128) void k2_slab(
    const float* __restrict__ part, const float* __restrict__ ps,
    const float* __restrict__ cen, float* __restrict__ flat)
{
    __shared__ float w2[2];
    const int b = blockIdx.x;        // n*64 + k
    const int n = b >> 6;
    const int k = b & 63;
    const int c = threadIdx.x;       // 0..127
    const float* pb = part + (size_t)n * NPT * KC * CC + (size_t)k * CC + c;
    float v = 0.f;
#pragma unroll 8
    for (int pt = 0; pt < NPT; ++pt) v += pb[(size_t)pt * KC * CC];
    const float* psb = ps + (size_t)n * NPT * KC + k;
    float sw = 0.f;
#pragma unroll
    for (int pt = 0; pt < NPT; ++pt) sw += psb[(size_t)pt * KC];
    v -= cen[(size_t)k * S1C * CC + c] * sw;

    float ss = v * v;
#pragma unroll
    for (int off = 32; off > 0; off >>= 1) ss += __shfl_down(ss, off);
    if ((c & 63) == 0) w2[c >> 6] = ss;
    __syncthreads();
    const float norm = sqrtf(w2[0] + w2[1]);
    // flat-level norm is exactly sqrt(64)=8 (every row unit-norm, >> EPS)
    const float scale = 1.0f / (fmaxf(norm, EPSF) * 8.0f);
    flat[(size_t)b * CC + c] = v * scale;
}

// ---------------------------------------------------------------------------
// k2 (fallback/atomic mode)
// ---------------------------------------------------------------------------
__global__ __launch_bounds__(128) void k2_final(
    const float* __restrict__ accC, const float* __restrict__ accS,
    const float* __restrict__ cen, float* __restrict__ flat)
{
    __shared__ float w2[2];
    const int b = blockIdx.x;
    const int k = b & 63;
    const int c = threadIdx.x;
    const float v = accC[(size_t)b * CC + c] -
                    cen[(size_t)k * S1C * CC + c] * accS[b];
    float ss = v * v;
#pragma unroll
    for (int off = 32; off > 0; off >>= 1) ss += __shfl_down(ss, off);
    if ((c & 63) == 0) w2[c >> 6] = ss;
    __syncthreads();
    const float norm = sqrtf(w2[0] + w2[1]);
    const float scale = 1.0f / (fmaxf(norm, EPSF) * 8.0f);
    flat[(size_t)b * CC + c] = v * scale;
}

// ---------------------------------------------------------------------------
extern "C" void kernel_launch(void* const* d_in, const int* in_sizes, int n_in,
                              void* d_out, int out_size, void* d_ws, size_t ws_size,
                              hipStream_t stream) {
    const float* x   = (const float*)d_in[0];   // [8][128][44][44]
    const float* cen = (const float*)d_in[1];   // [64][5][128]
    float* out  = (float*)d_out;
    float* flat = out;                           // [8][8192]
    float* sa   = out + (size_t)NB * KC * CC;    // [8][64][1][1936]
    float* ws   = (float*)d_ws;

    unsigned* cenPk = (unsigned*)ws;
    float*    gbias = ws + WS_CENPK;

    if (ws_size >= WS_MAIN_FLOATS * 4) {
        float* part = ws + WS_HDR;
        float* ps   = part + WS_PART;
        k0_pack<<<32, 64, 0, stream>>>(cen, cenPk, gbias);
        k1_main<<<NTILE, 1024, 0, stream>>>(x, cenPk, gbias, sa, part, ps, 0);
        k2_slab<<<NB * KC, 128, 0, stream>>>(part, ps, cen, flat);
    } else {
        float* accC = ws + WS_HDR;
        float* accS = accC + (size_t)NB * KC * CC;
        hipMemsetAsync(accC, 0, (size_t)(NB * KC * CC + NB * KC) * 4, stream);
        k0_pack<<<32, 64, 0, stream>>>(cen, cenPk, gbias);
        k1_main<<<NTILE, 1024, 0, stream>>>(x, cenPk, gbias, sa, accC, accS, 1);
        k2_final<<<NB * KC, 128, 0, stream>>>(accC, accS, cen, flat);
    }
}